// Round 11
// baseline (119.295 us; speedup 1.0000x reference)
//
#include <hip/hip_runtime.h>
#include <hip/hip_fp16.h>

#define NF 40
#define NE 128
#define NA 128
#define NP 780        // NF*(NF-1)/2
#define NPT 784       // padded to 49*16
#define NMT 49        // m-tiles of 16 pairs
#define XS_LD 132     // fp32 x LDS row stride (floats)
#define XS16_LD 136   // f16 x LDS row stride (ushorts)
#define G16_LD 72     // f16 G row stride: 144B rows -> 16B aligned, 2-way max conflicts

typedef _Float16 half8 __attribute__((ext_vector_type(8)));
typedef float floatx4 __attribute__((ext_vector_type(4)));

// sum across each 16-lane row via DPP row_ror (VALU pipe, no DS traffic)
__device__ __forceinline__ float rowsum16(float x) {
    x += __int_as_float(__builtin_amdgcn_update_dpp(0, __float_as_int(x), 0x121, 0xf, 0xf, true)); // ror:1
    x += __int_as_float(__builtin_amdgcn_update_dpp(0, __float_as_int(x), 0x122, 0xf, 0xf, true)); // ror:2
    x += __int_as_float(__builtin_amdgcn_update_dpp(0, __float_as_int(x), 0x124, 0xf, 0xf, true)); // ror:4
    x += __int_as_float(__builtin_amdgcn_update_dpp(0, __float_as_int(x), 0x128, 0xf, 0xf, true)); // ror:8
    return x;
}

// ---- prep: W fp32 -> f16 (RNE) into workspace; pair-index table ----
__global__ __launch_bounds__(256)
void afm_prep_kernel(const float* __restrict__ wg,
                     unsigned short* __restrict__ wbf,
                     int* __restrict__ ijg)
{
    const int t = blockIdx.x * 256 + threadIdx.x;   // 4096 threads
    if (t < NA * NE / 4) {
        float4 v = *(const float4*)(wg + t * 4);
        union { _Float16 h[4]; ushort4 u; } c;
        c.h[0] = (_Float16)v.x;
        c.h[1] = (_Float16)v.y;
        c.h[2] = (_Float16)v.z;
        c.h[3] = (_Float16)v.w;
        *(ushort4*)(wbf + t * 4) = c.u;
    }
    if (t < NPT) {
        int v = 0;
        if (t < NP) {
            int i = 0, rem = t;
            while (rem >= (NF - 1 - i)) { rem -= (NF - 1 - i); ++i; }
            v = (i << 8) | (i + 1 + rem);
        }
        ijg[t] = v;
    }
}

__global__ __launch_bounds__(256, 2)
void afm_fused_kernel(const float* __restrict__ xg,          // [B, F, E]
                      const unsigned short* __restrict__ wbf,// [A, E] f16 (prepped)
                      const int* __restrict__ ijg,           // [NPT] packed (i<<8)|j
                      const float* __restrict__ wbg,         // [A]
                      const float* __restrict__ hg,          // [1, A]
                      const float* __restrict__ pwg,         // [1, E]
                      const float* __restrict__ pbg,         // [1]
                      float* __restrict__ out)               // [B]
{
    __shared__ float          xs[NF][XS_LD];      // 21120 B fp32 x (afm epilogue path)
    __shared__ unsigned short xs16[NF][XS16_LD];  // 10880 B f16 x (MFMA path)
    __shared__ int      ij[NPT];                  // 3136 B
    __shared__ _Float16 G16[48][G16_LD];          // 6912 B f16 exp-weight matrix (padded, zero-filled)
    __shared__ float    afm1[NE];                 // 512 B final afm vector
    __shared__ float red_sum[4], red_out[2];

    const int tid  = threadIdx.x;
    const int b    = blockIdx.x;
    const int lane = tid & 63;
    const int wid  = tid >> 6;
    const int col  = lane & 15;
    const int quad = (lane >> 4) & 3;

    // ---- zero G16 (padding rows/cols + diag must be 0) ----
    for (int t = tid; t < 48 * G16_LD / 2; t += 256)
        ((unsigned*)&G16[0][0])[t] = 0u;

    // ---- stage x[b]: fp32 + f16 copies ----
    const float* xb = xg + (size_t)b * (NF * NE);
    for (int t = tid; t < NF * (NE / 4); t += 256) {
        int row = t >> 5, c = (t & 31) * 4;
        float4 v = *(const float4*)(xb + row * NE + c);
        *(float4*)&xs[row][c] = v;
        union { _Float16 h[4]; unsigned long long ull; } cv;
        cv.h[0] = (_Float16)v.x;
        cv.h[1] = (_Float16)v.y;
        cv.h[2] = (_Float16)v.z;
        cv.h[3] = (_Float16)v.w;
        *(unsigned long long*)&xs16[row][c] = cv.ull;
    }
    if (tid < NPT / 4) {
        *(int4*)&ij[tid * 4] = ((const int4*)ijg)[tid];
    }
    // ---- per-lane epilogue constants ----
    float wbr[8], hr[8];
#pragma unroll
    for (int n = 0; n < 8; ++n) {
        wbr[n] = wbg[n * 16 + col];
        hr[n]  = hg[n * 16 + col];
    }
    // ---- W B-fragments into registers ----
    half8 bfrag[8][4];
#pragma unroll
    for (int n = 0; n < 8; ++n)
#pragma unroll
        for (int k = 0; k < 4; ++k)
            bfrag[n][k] = *(const half8*)(const void*)(wbf + (n * 16 + col) * NE + k * 32 + quad * 8);
    __syncthreads();

    // ---- main MFMA loop; exp fused into epilogue (softmax max-shift cancels:
    //      scores ~ N(0,~1), f16 overflow needs score>11 -- unreachable) ----
    float esum = 0.f;
    for (int mt = wid; mt < NMT; mt += 4) {
        const int p0 = mt * 16;
        const int v  = ij[p0 + col];
        const unsigned short* xi16 = &xs16[(v >> 8) & 255][0];
        const unsigned short* xj16 = &xs16[v & 255][0];

        floatx4 acc[8];
#pragma unroll
        for (int n = 0; n < 8; ++n)
            acc[n] = (floatx4){wbr[n], wbr[n], wbr[n], wbr[n]};  // bias folded into C-init

#pragma unroll
        for (int k = 0; k < 4; ++k) {
            const int koff = k * 32 + quad * 8;
            half8 ih = *(const half8*)(const void*)(xi16 + koff);
            half8 jh = *(const half8*)(const void*)(xj16 + koff);
            half8 af = ih * jh;
#pragma unroll
            for (int n = 0; n < 8; ++n)
                acc[n] = __builtin_amdgcn_mfma_f32_16x16x32_f16(af, bfrag[n][k], acc[n], 0, 0, 0);
        }

        // scores[p] = sum_a relu(S[p,a]) * h[a]; then e = exp(score) directly
        float ps[4] = {0.f, 0.f, 0.f, 0.f};
#pragma unroll
        for (int n = 0; n < 8; ++n) {
#pragma unroll
            for (int r = 0; r < 4; ++r)
                ps[r] += fmaxf(acc[n][r], 0.f) * hr[n];
        }
#pragma unroll
        for (int r = 0; r < 4; ++r) ps[r] = rowsum16(ps[r]);

#pragma unroll
        for (int r = 0; r < 4; ++r) {
            const int p = p0 + quad * 4 + r;
            const float e = __expf(ps[r]);        // unshifted; see note above
            if (col == 0 && p < NP) {
                const int vv = ij[p];
                const _Float16 eh = (_Float16)e;
                G16[(vv >> 8) & 255][vv & 255] = eh;
                G16[vv & 255][(vv >> 8) & 255] = eh;
                esum += e;
            }
        }
    }
#pragma unroll
    for (int off = 1; off < 64; off <<= 1) esum += __shfl_xor(esum, off);
    if (lane == 0) red_sum[wid] = esum;
    __syncthreads();   // G16 + red_sum complete

    // ---- afm via MFMA: Y = G16 * X; afm[e] = 0.5 * sum_i X[i,e] * Y[i,e] ----
    // wave owns e-tiles {2*wid, 2*wid+1}; M padded to 48, K padded to 64 (zeros in G16)
    {
        const int n0 = wid * 2;
        float af0 = 0.f, af1 = 0.f;
#pragma unroll
        for (int mt = 0; mt < 3; ++mt) {
            const int arow = mt * 16 + col;
            half8 a1 = *(const half8*)(const void*)&G16[arow][quad * 8];        // k 0..31
            half8 a2 = *(const half8*)(const void*)&G16[arow][32 + quad * 8];   // k 32..63 (>=40 zero)
#pragma unroll
            for (int nt = 0; nt < 2; ++nt) {
                const int ecol = (n0 + nt) * 16 + col;
                union { half8 h; unsigned short u[8]; } b1, b2;
#pragma unroll
                for (int j = 0; j < 8; ++j)
                    b1.u[j] = xs16[quad * 8 + j][ecol];       // k rows 0..31
#pragma unroll
                for (int j = 0; j < 8; ++j)
                    b2.u[j] = 0;
                if (quad == 0) {
#pragma unroll
                    for (int j = 0; j < 8; ++j)
                        b2.u[j] = xs16[32 + j][ecol];         // k rows 32..39; rest A=0
                }
                floatx4 y = (floatx4){0.f, 0.f, 0.f, 0.f};
                y = __builtin_amdgcn_mfma_f32_16x16x32_f16(a1, b1.h, y, 0, 0, 0);
                y = __builtin_amdgcn_mfma_f32_16x16x32_f16(a2, b2.h, y, 0, 0, 0);
                // C layout: col = lane&15, row = quad*4 + r (within m-tile)
                if (mt * 16 + quad * 4 < NF) {                // skip all-pad row quads
                    float acc = 0.f;
#pragma unroll
                    for (int r = 0; r < 4; ++r)
                        acc += xs[mt * 16 + quad * 4 + r][ecol] * y[r];
                    if (nt == 0) af0 += acc; else af1 += acc;
                }
            }
        }
        // reduce over quads (rows); every lane ends with full row-sum
        af0 += __shfl_xor(af0, 16);  af0 += __shfl_xor(af0, 32);
        af1 += __shfl_xor(af1, 16);  af1 += __shfl_xor(af1, 32);
        if (lane < 16) {
            afm1[(n0 + 0) * 16 + lane] = af0 * 0.5f;
            afm1[(n0 + 1) * 16 + lane] = af1 * 0.5f;
        }
    }
    __syncthreads();

    // ---- out[b] = (sum_e afm_un[e] * pw[e]) / sum_exp + p_b ----
    float vv = 0.f;
    if (tid < NE) vv = afm1[tid] * pwg[tid];
#pragma unroll
    for (int off = 1; off < 64; off <<= 1) vv += __shfl_xor(vv, off);
    if (lane == 0 && wid < 2) red_out[wid] = vv;
    __syncthreads();
    if (tid == 0) {
        float S   = red_sum[0] + red_sum[1] + red_sum[2] + red_sum[3];
        float tot = red_out[0] + red_out[1];
        out[b] = tot / S + pbg[0];
    }
}

extern "C" void kernel_launch(void* const* d_in, const int* in_sizes, int n_in,
                              void* d_out, int out_size, void* d_ws, size_t ws_size,
                              hipStream_t stream) {
    const float* xg  = (const float*)d_in[0];  // x [B,F,E]
    const float* wg  = (const float*)d_in[1];  // attn_w_w [A,E]
    const float* wbg = (const float*)d_in[2];  // attn_w_b [A]
    const float* hg  = (const float*)d_in[3];  // attn_h_w [1,A]
    // d_in[4] = attn_h_b : constant shift, cancels in softmax
    const float* pwg = (const float*)d_in[5];  // attn_p_w [1,E]
    const float* pbg = (const float*)d_in[6];  // attn_p_b [1]
    const int B = in_sizes[0] / (NF * NE);

    unsigned short* wbf = (unsigned short*)d_ws;                        // 32768 B (f16 W)
    int* ijg = (int*)((char*)d_ws + NA * NE * sizeof(unsigned short));  // 3136 B

    afm_prep_kernel<<<16, 256, 0, stream>>>(wg, wbf, ijg);
    afm_fused_kernel<<<B, 256, 0, stream>>>(xg, wbf, ijg, wbg, hg, pwg, pbg, (float*)d_out);
}

// Round 12
// 112.315 us; speedup vs baseline: 1.0621x; 1.0621x over previous
//
#include <hip/hip_runtime.h>
#include <hip/hip_fp16.h>

#define NF 40
#define NE 128
#define NA 128
#define NW 144        // extended W rows: 128 W + 1 pw + 15 zero
#define NP 780        // NF*(NF-1)/2
#define NPT 784       // padded to 49*16
#define NMT 49        // m-tiles of 16 pairs
#define XS16_LD 136   // f16 x LDS row stride (ushorts): 272B rows, 16B aligned

typedef _Float16 half8 __attribute__((ext_vector_type(8)));
typedef float floatx4 __attribute__((ext_vector_type(4)));

// sum across each 16-lane row via DPP row_ror (VALU pipe, no DS traffic)
__device__ __forceinline__ float rowsum16(float x) {
    x += __int_as_float(__builtin_amdgcn_update_dpp(0, __float_as_int(x), 0x121, 0xf, 0xf, true)); // ror:1
    x += __int_as_float(__builtin_amdgcn_update_dpp(0, __float_as_int(x), 0x122, 0xf, 0xf, true)); // ror:2
    x += __int_as_float(__builtin_amdgcn_update_dpp(0, __float_as_int(x), 0x124, 0xf, 0xf, true)); // ror:4
    x += __int_as_float(__builtin_amdgcn_update_dpp(0, __float_as_int(x), 0x128, 0xf, 0xf, true)); // ror:8
    return x;
}

// ---- prep: [W; pw; 0] fp32 -> f16 (RNE) extended matrix; pair-index table ----
__global__ __launch_bounds__(256)
void afm_prep_kernel(const float* __restrict__ wg,
                     const float* __restrict__ pwg,
                     unsigned short* __restrict__ wbf,   // [NW][NE] f16
                     int* __restrict__ ijg)
{
    const int t = blockIdx.x * 256 + threadIdx.x;   // 20*256 = 5120 threads
    if (t < NW * NE / 4) {                          // 4608
        const int row = t >> 5;                     // /(NE/4)
        const int c   = (t & 31) * 4;
        float4 v = make_float4(0.f, 0.f, 0.f, 0.f);
        if (row < NA)       v = *(const float4*)(wg + row * NE + c);
        else if (row == NA) v = *(const float4*)(pwg + c);
        union { _Float16 h[4]; ushort4 u; } cv;
        cv.h[0] = (_Float16)v.x;
        cv.h[1] = (_Float16)v.y;
        cv.h[2] = (_Float16)v.z;
        cv.h[3] = (_Float16)v.w;
        *(ushort4*)(wbf + t * 4) = cv.u;
    }
    if (t < NPT) {
        int v = 0;
        if (t < NP) {
            int i = 0, rem = t;
            while (rem >= (NF - 1 - i)) { rem -= (NF - 1 - i); ++i; }
            v = (i << 8) | (i + 1 + rem);
        }
        ijg[t] = v;
    }
}

// out[b] = (sum_p e_p * Q_p) / (sum_p e_p) + pb, with Q_p = sum_e hp[p,e]*pw[e]
// computed as a 9th B-tile of the main MFMA. No afm vector, no G matrix.
__global__ __launch_bounds__(256, 2)
void afm_fused_kernel(const float* __restrict__ xg,          // [B, F, E]
                      const unsigned short* __restrict__ wbf,// [NW, E] f16 (prepped)
                      const int* __restrict__ ijg,           // [NPT] packed (i<<8)|j
                      const float* __restrict__ wbg,         // [A]
                      const float* __restrict__ hg,          // [1, A]
                      const float* __restrict__ pbg,         // [1]
                      float* __restrict__ out)               // [B]
{
    __shared__ unsigned short xs16[NF][XS16_LD];  // 10880 B f16 x
    __shared__ int   ij[NPT];                     // 3136 B
    __shared__ float red_n[4], red_d[4];

    const int tid  = threadIdx.x;
    const int b    = blockIdx.x;
    const int lane = tid & 63;
    const int wid  = tid >> 6;
    const int col  = lane & 15;
    const int quad = (lane >> 4) & 3;

    // ---- stage x[b] as f16 ----
    const float* xb = xg + (size_t)b * (NF * NE);
    for (int t = tid; t < NF * (NE / 4); t += 256) {
        int row = t >> 5, c = (t & 31) * 4;
        float4 v = *(const float4*)(xb + row * NE + c);
        union { _Float16 h[4]; unsigned long long ull; } cv;
        cv.h[0] = (_Float16)v.x;
        cv.h[1] = (_Float16)v.y;
        cv.h[2] = (_Float16)v.z;
        cv.h[3] = (_Float16)v.w;
        *(unsigned long long*)&xs16[row][c] = cv.ull;   // 8B store, 8B aligned
    }
    if (tid < NPT / 4) {
        *(int4*)&ij[tid * 4] = ((const int4*)ijg)[tid];
    }
    // ---- per-lane epilogue constants ----
    float wbr[8], hr[8];
#pragma unroll
    for (int n = 0; n < 8; ++n) {
        wbr[n] = wbg[n * 16 + col];
        hr[n]  = hg[n * 16 + col];
    }
    // ---- extended-W B-fragments into registers (n=8 is the pw tile) ----
    half8 bfrag[9][4];
#pragma unroll
    for (int n = 0; n < 9; ++n)
#pragma unroll
        for (int k = 0; k < 4; ++k)
            bfrag[n][k] = *(const half8*)(const void*)(wbf + (n * 16 + col) * NE + k * 32 + quad * 8);
    __syncthreads();

    // ---- single fused loop: scores, exp, and Q all from one MFMA pass ----
    // unshifted exp is safe: scores ~ N(0,~1); fp32 overflow needs score > 88
    float nloc = 0.f, dloc = 0.f;
    for (int mt = wid; mt < NMT; mt += 4) {
        const int p0 = mt * 16;
        const int v  = ij[p0 + col];
        const unsigned short* xi16 = &xs16[(v >> 8) & 255][0];
        const unsigned short* xj16 = &xs16[v & 255][0];

        floatx4 acc[9];
#pragma unroll
        for (int n = 0; n < 8; ++n)
            acc[n] = (floatx4){wbr[n], wbr[n], wbr[n], wbr[n]};  // bias folded into C-init
        acc[8] = (floatx4){0.f, 0.f, 0.f, 0.f};                  // Q accumulator

#pragma unroll
        for (int k = 0; k < 4; ++k) {
            const int koff = k * 32 + quad * 8;
            half8 ih = *(const half8*)(const void*)(xi16 + koff);
            half8 jh = *(const half8*)(const void*)(xj16 + koff);
            half8 af = ih * jh;
#pragma unroll
            for (int n = 0; n < 9; ++n)
                acc[n] = __builtin_amdgcn_mfma_f32_16x16x32_f16(af, bfrag[n][k], acc[n], 0, 0, 0);
        }

        // score[p] = sum_a relu(S[p,a]) * h[a];  Q[p] = acc[8][r] at col==0
        float ps[4] = {0.f, 0.f, 0.f, 0.f};
#pragma unroll
        for (int n = 0; n < 8; ++n) {
#pragma unroll
            for (int r = 0; r < 4; ++r)
                ps[r] += fmaxf(acc[n][r], 0.f) * hr[n];
        }
#pragma unroll
        for (int r = 0; r < 4; ++r) ps[r] = rowsum16(ps[r]);

#pragma unroll
        for (int r = 0; r < 4; ++r) {
            const int p = p0 + quad * 4 + r;
            const float e = __expf(ps[r]);             // unshifted; fp32 throughout
            const bool valid = (col == 0) & (p < NP);
            if (valid) {
                nloc += e * acc[8][r];
                dloc += e;
            }
        }
    }
#pragma unroll
    for (int off = 1; off < 64; off <<= 1) {
        nloc += __shfl_xor(nloc, off);
        dloc += __shfl_xor(dloc, off);
    }
    if (lane == 0) { red_n[wid] = nloc; red_d[wid] = dloc; }
    __syncthreads();
    if (tid == 0) {
        float N = red_n[0] + red_n[1] + red_n[2] + red_n[3];
        float D = red_d[0] + red_d[1] + red_d[2] + red_d[3];
        out[b] = N / D + pbg[0];
    }
}

extern "C" void kernel_launch(void* const* d_in, const int* in_sizes, int n_in,
                              void* d_out, int out_size, void* d_ws, size_t ws_size,
                              hipStream_t stream) {
    const float* xg  = (const float*)d_in[0];  // x [B,F,E]
    const float* wg  = (const float*)d_in[1];  // attn_w_w [A,E]
    const float* wbg = (const float*)d_in[2];  // attn_w_b [A]
    const float* hg  = (const float*)d_in[3];  // attn_h_w [1,A]
    // d_in[4] = attn_h_b : constant shift, cancels in softmax
    const float* pwg = (const float*)d_in[5];  // attn_p_w [1,E]
    const float* pbg = (const float*)d_in[6];  // attn_p_b [1]
    const int B = in_sizes[0] / (NF * NE);

    unsigned short* wbf = (unsigned short*)d_ws;                        // 36864 B ([144][128] f16)
    int* ijg = (int*)((char*)d_ws + NW * NE * sizeof(unsigned short));  // 3136 B

    afm_prep_kernel<<<20, 256, 0, stream>>>(wg, pwg, wbf, ijg);
    afm_fused_kernel<<<B, 256, 0, stream>>>(xg, wbf, ijg, wbg, hg, pbg, (float*)d_out);
}